// Round 8
// baseline (349.287 us; speedup 1.0000x reference)
//
#include <hip/hip_runtime.h>
#include <math.h>

#define N_DET 512
#define N_TRK 512
#define NPTS  256

typedef __attribute__((ext_vector_type(8))) short short8;
typedef __attribute__((ext_vector_type(4))) float f32x4;
typedef unsigned short ushort_t;

__device__ __forceinline__ float sigm(float x) { return 1.f / (1.f + expf(-x)); }

__device__ __forceinline__ unsigned short f2bf(float f) {
    unsigned u = __float_as_uint(f);
    u += 0x7FFF + ((u >> 16) & 1);          // round-to-nearest-even
    return (unsigned short)(u >> 16);
}
__device__ __forceinline__ float bf2f(unsigned short h) {
    return __uint_as_float(((unsigned)h) << 16);
}

// ---------------------------------------------------------------------------
// Pack pointnet w2/w3 into MFMA B-fragment-major bf16.
// ---------------------------------------------------------------------------
__global__ __launch_bounds__(64) void pn_wprep_kernel(
    const float* __restrict__ w2, const float* __restrict__ w3,
    unsigned short* __restrict__ wfrag)
{
    const int f = blockIdx.x;          // 48
    const int lane = threadIdx.x;      // 64
    const int lm = lane & 15, lg = lane >> 4;
    const float* src;
    if (f < 16) {
        const int s = f >> 3, n = f & 7;
        src = w2 + (size_t)(n*16 + lm)*64 + s*32 + lg*8;
    } else {
        const int f2 = f - 16, s = f2 >> 3, n = f2 & 7;
        src = w3 + (size_t)(n*16 + lm)*128 + s*32 + lg*8;
    }
    short8 v;
#pragma unroll
    for (int j = 0; j < 8; ++j) v[j] = (short)f2bf(src[j]);
    *reinterpret_cast<short8*>(wfrag + ((size_t)f*64 + lane)*8) = v;
}

// ---------------------------------------------------------------------------
// Pack EdgeConv W=[tw;pw] (per layer, [512][256]) into frag-major bf16 hi/lo.
// ---------------------------------------------------------------------------
__global__ __launch_bounds__(64) void ec_wprep_kernel(
    const float* __restrict__ tw, const float* __restrict__ pw,
    unsigned short* __restrict__ whi, unsigned short* __restrict__ wlo)
{
    const int id = blockIdx.x;                 // 1024 = 4 layers * 32 ntiles * 8 kf
    const int layer = id >> 8;
    const int ntile = (id >> 3) & 31, kf = id & 7;
    const int lane = threadIdx.x;
    const int lm = lane & 15, lg = lane >> 4;
    const int col = ntile*16 + lm, k = kf*32 + lg*8;
    const float* src = (col < 256)
        ? tw + ((size_t)layer*256 + col)*256 + k
        : pw + ((size_t)layer*256 + (col - 256))*256 + k;
    short8 hi, lo;
#pragma unroll
    for (int j = 0; j < 8; ++j) {
        const float f = src[j];
        const unsigned short h = f2bf(f);
        hi[j] = (short)h;
        lo[j] = (short)f2bf(f - bf2f(h));
    }
    const size_t off = ((size_t)id*64 + lane)*8;
    *reinterpret_cast<short8*>(whi + off) = hi;
    *reinterpret_cast<short8*>(wlo + off) = lo;
}

// ---------------------------------------------------------------------------
// Pack LSTM whh0 / wih1 / whh1 ([512][128] each) into B-frag bf16 (hi only).
// ---------------------------------------------------------------------------
__global__ __launch_bounds__(64) void lstm_wprep_kernel(
    const float* __restrict__ whh0, const float* __restrict__ wih1,
    const float* __restrict__ whh1, unsigned short* __restrict__ wf)
{
    const int id = blockIdx.x;                  // 384
    const int mat = id >> 7, rest = id & 127;
    const int nt = rest >> 2, kf = rest & 3;
    const int lane = threadIdx.x;
    const int lm = lane & 15, lg = lane >> 4;
    const float* src = (mat == 0) ? whh0 : ((mat == 1) ? wih1 : whh1);
    const float* p = src + (size_t)(nt*16 + lm)*128 + kf*32 + lg*8;
    short8 v;
#pragma unroll
    for (int j = 0; j < 8; ++j) v[j] = (short)f2bf(p[j]);
    *reinterpret_cast<short8*>(wf + ((size_t)id*64 + lane)*8) = v;
}

// ---------------------------------------------------------------------------
// xg0[bt][512] = xseq[bt][9] @ wih0^T
// ---------------------------------------------------------------------------
__global__ __launch_bounds__(512) void lstm_xg0_kernel(
    const float* __restrict__ xseq, const float* __restrict__ wih0,
    float* __restrict__ xg0)
{
    __shared__ float xs[8][12];
    const int tid = threadIdx.x;
    const int m0 = blockIdx.x * 8;              // grid 640
    if (tid < 72) xs[tid / 9][tid % 9] = xseq[(size_t)m0*9 + tid];
    float wx[9];
#pragma unroll
    for (int c = 0; c < 9; ++c) wx[c] = wih0[tid*9 + c];
    __syncthreads();
#pragma unroll
    for (int i = 0; i < 8; ++i) {
        float s = 0.f;
#pragma unroll
        for (int c = 0; c < 9; ++c) s = fmaf(wx[c], xs[i][c], s);
        xg0[(size_t)(m0 + i)*512 + tid] = s;
    }
}

// ---------------------------------------------------------------------------
// xg1[bt][512] = h0seq[bt][128] @ wih1^T via split-bf16 MFMA.
// ---------------------------------------------------------------------------
__global__ __launch_bounds__(256) void lstm_xg1_kernel(
    const unsigned short* __restrict__ h0hi, const unsigned short* __restrict__ h0lo,
    const unsigned short* __restrict__ wfrag, float* __restrict__ xg1)
{
    const int tid = threadIdx.x, lane = tid & 63, w = tid >> 6;
    const int lm = lane & 15, lg = lane >> 4;
    const int m0 = blockIdx.x*64 + w*16;
    const int bn = blockIdx.y;
    const int arow = m0 + lm;
    short8 ahi[4], alo[4];
#pragma unroll
    for (int kf = 0; kf < 4; ++kf) {
        ahi[kf] = *reinterpret_cast<const short8*>(h0hi + (size_t)arow*128 + kf*32 + lg*8);
        alo[kf] = *reinterpret_cast<const short8*>(h0lo + (size_t)arow*128 + kf*32 + lg*8);
    }
#pragma unroll
    for (int nt = 0; nt < 4; ++nt) {
        f32x4 acc = {0.f, 0.f, 0.f, 0.f};
#pragma unroll
        for (int kf = 0; kf < 4; ++kf) {
            const short8 bf = *reinterpret_cast<const short8*>(
                wfrag + ((size_t)((bn*4 + nt)*4 + kf)*64 + lane)*8);
            acc = __builtin_amdgcn_mfma_f32_16x16x32_bf16(ahi[kf], bf, acc, 0, 0, 0);
            acc = __builtin_amdgcn_mfma_f32_16x16x32_bf16(alo[kf], bf, acc, 0, 0, 0);
        }
#pragma unroll
        for (int r = 0; r < 4; ++r)
            xg1[(size_t)(m0 + lg*4 + r)*512 + bn*64 + nt*16 + lm] = acc[r];
    }
}

// ---------------------------------------------------------------------------
// LSTM recurrent step kernel (MFMA). 32 blocks x 512 thr, 16 batches/block.
// ---------------------------------------------------------------------------
template<int LAYER>
__global__ __launch_bounds__(512, 2) void lstm_mfma_kernel(
    const unsigned short* __restrict__ wfrag,
    const float* __restrict__ xg, const float* __restrict__ bias,
    unsigned short* __restrict__ h0hi, unsigned short* __restrict__ h0lo,
    float* __restrict__ hout)
{
    __shared__ unsigned short hfhi[4*64*8];
    __shared__ unsigned short hflo[4*64*8];
    __shared__ float gs[512*20];

    const int tid = threadIdx.x;
    const int lane = tid & 63, w = tid >> 6;
    const int lm = lane & 15, lg = lane >> 4;
    const int b0 = blockIdx.x * 16;

    short8 wf[4][4];
#pragma unroll
    for (int nt = 0; nt < 4; ++nt)
#pragma unroll
        for (int kf = 0; kf < 4; ++kf)
            wf[nt][kf] = *reinterpret_cast<const short8*>(
                wfrag + ((size_t)((w*4 + nt)*4 + kf)*64 + lane)*8);

    for (int i = tid; i < 2048; i += 512) { hfhi[i] = 0; hflo[i] = 0; }

    const int mj = tid & 127;
    const int mb0 = (tid >> 7) * 4;
    const float bi = bias[mj], bf_ = bias[128 + mj];
    const float bg = bias[256 + mj], bo = bias[384 + mj];
    const int hkf = mj >> 5, hlg = (mj >> 3) & 3, hjj = mj & 7;
    float c[4] = {0.f, 0.f, 0.f, 0.f};

    __syncthreads();

    for (int t = 0; t < 10; ++t) {
        float xgv[4][4];
#pragma unroll
        for (int s = 0; s < 4; ++s) {
            const size_t btg = ((size_t)(b0 + mb0 + s)*10 + t)*512;
            xgv[s][0] = xg[btg + mj];
            xgv[s][1] = xg[btg + 128 + mj];
            xgv[s][2] = xg[btg + 256 + mj];
            xgv[s][3] = xg[btg + 384 + mj];
        }
        short8 ahi[4], alo[4];
#pragma unroll
        for (int kf = 0; kf < 4; ++kf) {
            ahi[kf] = *reinterpret_cast<const short8*>(&hfhi[(kf*64 + lane)*8]);
            alo[kf] = *reinterpret_cast<const short8*>(&hflo[(kf*64 + lane)*8]);
        }
#pragma unroll
        for (int nt = 0; nt < 4; ++nt) {
            f32x4 acc = {0.f, 0.f, 0.f, 0.f};
#pragma unroll
            for (int kf = 0; kf < 4; ++kf) {
                acc = __builtin_amdgcn_mfma_f32_16x16x32_bf16(ahi[kf], wf[nt][kf], acc, 0, 0, 0);
                acc = __builtin_amdgcn_mfma_f32_16x16x32_bf16(alo[kf], wf[nt][kf], acc, 0, 0, 0);
            }
            const int g = w*64 + nt*16 + lm;
            float4 tmp; tmp.x = acc[0]; tmp.y = acc[1]; tmp.z = acc[2]; tmp.w = acc[3];
            *(float4*)&gs[g*20 + lg*4] = tmp;
        }
        __syncthreads();
#pragma unroll
        for (int s = 0; s < 4; ++s) {
            const int b = mb0 + s;
            const float gi = gs[mj*20 + b]         + xgv[s][0] + bi;
            const float gf = gs[(128 + mj)*20 + b] + xgv[s][1] + bf_;
            const float gg = gs[(256 + mj)*20 + b] + xgv[s][2] + bg;
            const float go = gs[(384 + mj)*20 + b] + xgv[s][3] + bo;
            c[s] = sigm(gf)*c[s] + sigm(gi)*tanhf(gg);
            const float hn = sigm(go)*tanhf(c[s]);
            const unsigned short hh = f2bf(hn);
            const unsigned short hl = f2bf(hn - bf2f(hh));
            hfhi[(hkf*64 + hlg*16 + b)*8 + hjj] = hh;
            hflo[(hkf*64 + hlg*16 + b)*8 + hjj] = hl;
            if constexpr (LAYER == 0) {
                h0hi[((size_t)(b0 + b)*10 + t)*128 + mj] = hh;
                h0lo[((size_t)(b0 + b)*10 + t)*128 + mj] = hl;
            } else {
                if (t == 9)
                    hout[(size_t)(N_DET + b0 + b)*256 + 128 + mj] = hn;
            }
        }
        __syncthreads();
    }
}

// ---------------------------------------------------------------------------
// h (fp32 [1024][256]) -> split-bf16 shadow (hi, lo).
// ---------------------------------------------------------------------------
__global__ __launch_bounds__(256) void h2bf_kernel(
    const float* __restrict__ h,
    unsigned short* __restrict__ hi, unsigned short* __restrict__ lo)
{
    const int id = blockIdx.x * 256 + threadIdx.x;
    const float4 v = *(const float4*)(h + (size_t)id*4);
    ushort_t h4[4], l4[4];
    const float vv[4] = {v.x, v.y, v.z, v.w};
#pragma unroll
    for (int j = 0; j < 4; ++j) {
        h4[j] = f2bf(vv[j]);
        l4[j] = f2bf(vv[j] - bf2f(h4[j]));
    }
    *(ulong1*)(hi + (size_t)id*4) = *(ulong1*)h4;
    *(ulong1*)(lo + (size_t)id*4) = *(ulong1*)l4;
}

// ---------------------------------------------------------------------------
// PointNet fused MFMA kernel, tile-streamed LDS (one box/block, 4 waves).
// L1 in registers (bf16-packed). Per 16-point m-tile: stage h1 tile -> L2
// MFMA -> h2 tile -> L3 MFMA -> maxpool accumulate. LDS ~29 KB -> 5 blk/CU.
// ---------------------------------------------------------------------------
__global__ __launch_bounds__(256) void pointnet_mfma_kernel(
    const float* __restrict__ det_pc, const float* __restrict__ trk_pc,
    const float* __restrict__ w1, const float* __restrict__ b1,
    const unsigned short* __restrict__ wfrag,
    const float* __restrict__ b2, const float* __restrict__ b3,
    float* __restrict__ hout)
{
    __shared__ unsigned short h1t[4][16][72];    // per-wave h1 tile, 9.2 KB
    __shared__ unsigned short h2t[4][16][136];   // per-wave h2 tile, 17.4 KB
    __shared__ float wmaxs[4][128];

    const int tid = threadIdx.x;
    const int box = blockIdx.x;
    const int lane = tid & 63, w = tid >> 6;
    const int lm = lane & 15, lg = lane >> 4;

    // ---- L1: thread = point; 64 channels packed bf16 in 32 u32 regs ----
    const float* pc = (box < N_DET) ? det_pc + ((size_t)box*NPTS + tid)*3
                                    : trk_pc + ((size_t)(box - N_DET)*NPTS + tid)*3;
    const float x = pc[0], y = pc[1], z = pc[2];
    unsigned h1p[32];
#pragma unroll
    for (int j = 0; j < 32; ++j) {
        const int c0 = 2*j, c1 = 2*j + 1;
        float s0 = fmaf(w1[c0*3+0], x, fmaf(w1[c0*3+1], y, fmaf(w1[c0*3+2], z, b1[c0])));
        float s1 = fmaf(w1[c1*3+0], x, fmaf(w1[c1*3+1], y, fmaf(w1[c1*3+2], z, b1[c1])));
        h1p[j] = (unsigned)f2bf(fmaxf(s0, 0.f)) | ((unsigned)f2bf(fmaxf(s1, 0.f)) << 16);
    }

    // ---- w2 fragments resident in VGPRs ----
    short8 w2f[16];
#pragma unroll
    for (int f = 0; f < 16; ++f)
        w2f[f] = *reinterpret_cast<const short8*>(wfrag + ((size_t)f*64 + lane)*8);
    float b2v[8];
#pragma unroll
    for (int n = 0; n < 8; ++n) b2v[n] = b2[n*16 + lm];

    float pm[8];
#pragma unroll
    for (int n = 0; n < 8; ++n) pm[n] = -3.0e38f;

    for (int t = 0; t < 4; ++t) {
        __syncthreads();     // previous tile's reads done; safe to restage
        if (lg == t) {
#pragma unroll
            for (int q = 0; q < 8; ++q) {
                uint4 v;
                v.x = h1p[q*4+0]; v.y = h1p[q*4+1];
                v.z = h1p[q*4+2]; v.w = h1p[q*4+3];
                *(uint4*)&h1t[w][lm][q*8] = v;
            }
        }
        __syncthreads();
        // ---- L2 on tile: [16 pts x 64] @ w2^T ----
        const short8 a0 = *reinterpret_cast<const short8*>(&h1t[w][lm][lg*8]);
        const short8 a1 = *reinterpret_cast<const short8*>(&h1t[w][lm][32 + lg*8]);
#pragma unroll
        for (int n = 0; n < 8; ++n) {
            f32x4 acc = {0.f, 0.f, 0.f, 0.f};
            acc = __builtin_amdgcn_mfma_f32_16x16x32_bf16(a0, w2f[n],     acc, 0, 0, 0);
            acc = __builtin_amdgcn_mfma_f32_16x16x32_bf16(a1, w2f[8 + n], acc, 0, 0, 0);
#pragma unroll
            for (int r = 0; r < 4; ++r) {
                const float v = fmaxf(acc[r] + b2v[n], 0.f);
                h2t[w][lg*4 + r][n*16 + lm] = f2bf(v);
            }
        }
        __syncthreads();
        // ---- L3 on tile: [16 pts x 128] @ w3^T, maxpool accumulate ----
        const short8 c0 = *reinterpret_cast<const short8*>(&h2t[w][lm][  0 + lg*8]);
        const short8 c1 = *reinterpret_cast<const short8*>(&h2t[w][lm][ 32 + lg*8]);
        const short8 c2 = *reinterpret_cast<const short8*>(&h2t[w][lm][ 64 + lg*8]);
        const short8 c3 = *reinterpret_cast<const short8*>(&h2t[w][lm][ 96 + lg*8]);
#pragma unroll
        for (int n = 0; n < 8; ++n) {
            f32x4 acc = {0.f, 0.f, 0.f, 0.f};
            const short8 b0f = *reinterpret_cast<const short8*>(wfrag + ((size_t)(16 +      n)*64 + lane)*8);
            const short8 b1f = *reinterpret_cast<const short8*>(wfrag + ((size_t)(16 +  8 + n)*64 + lane)*8);
            const short8 b2f = *reinterpret_cast<const short8*>(wfrag + ((size_t)(16 + 16 + n)*64 + lane)*8);
            const short8 b3f = *reinterpret_cast<const short8*>(wfrag + ((size_t)(16 + 24 + n)*64 + lane)*8);
            acc = __builtin_amdgcn_mfma_f32_16x16x32_bf16(c0, b0f, acc, 0, 0, 0);
            acc = __builtin_amdgcn_mfma_f32_16x16x32_bf16(c1, b1f, acc, 0, 0, 0);
            acc = __builtin_amdgcn_mfma_f32_16x16x32_bf16(c2, b2f, acc, 0, 0, 0);
            acc = __builtin_amdgcn_mfma_f32_16x16x32_bf16(c3, b3f, acc, 0, 0, 0);
#pragma unroll
            for (int r = 0; r < 4; ++r) pm[n] = fmaxf(pm[n], acc[r]);
        }
    }

#pragma unroll
    for (int n = 0; n < 8; ++n) {
        float v = pm[n];
        v = fmaxf(v, __shfl_xor(v, 16, 64));
        v = fmaxf(v, __shfl_xor(v, 32, 64));
        pm[n] = v;
    }
    if (lg == 0) {
#pragma unroll
        for (int n = 0; n < 8; ++n) wmaxs[w][n*16 + lm] = pm[n];
    }
    __syncthreads();
    if (tid < 128) {
        const float m = fmaxf(fmaxf(wmaxs[0][tid], wmaxs[1][tid]),
                              fmaxf(wmaxs[2][tid], wmaxs[3][tid]));
        hout[(size_t)box*256 + tid] = fmaxf(m + b3[tid], 0.f);
    }
}

// ---------------------------------------------------------------------------
// det motion MLP: 9 -> 64 (relu) -> 128. One block per det.
// ---------------------------------------------------------------------------
__global__ __launch_bounds__(128) void detmlp_kernel(
    const float* __restrict__ boxes,
    const float* __restrict__ w1, const float* __restrict__ b1,
    const float* __restrict__ w2, const float* __restrict__ b2,
    float* __restrict__ hout)
{
    __shared__ float xb[9];
    __shared__ float h1[64];
    const int b = blockIdx.x, t = threadIdx.x;
    if (t < 9) xb[t] = boxes[b*9 + t];
    __syncthreads();
    if (t < 64) {
        float s = b1[t];
#pragma unroll
        for (int c = 0; c < 9; ++c) s = fmaf(w1[t*9+c], xb[c], s);
        h1[t] = fmaxf(s, 0.f);
    }
    __syncthreads();
    float s = b2[t];
    const float* wr = w2 + t*64;
#pragma unroll
    for (int c = 0; c < 64; ++c) s = fmaf(wr[c], h1[c], s);
    hout[(size_t)b * 256 + 128 + t] = s;
}

// ---------------------------------------------------------------------------
// EdgeConv GEMM via split-bf16 MFMA (3-product, fp32-grade).
// ---------------------------------------------------------------------------
__global__ __launch_bounds__(256) void ec_gemm_mfma_kernel(
    const unsigned short* __restrict__ hhi, const unsigned short* __restrict__ hlo,
    const unsigned short* __restrict__ whi, const unsigned short* __restrict__ wlo,
    const float* __restrict__ tb, const float* __restrict__ pb,
    float* __restrict__ Abuf, float* __restrict__ Bbuf,
    float* __restrict__ phiT, float* __restrict__ hnext,
    unsigned short* __restrict__ nhi, unsigned short* __restrict__ nlo)
{
    const int bm = blockIdx.x, bn = blockIdx.y;
    const int tid = threadIdx.x, lane = tid & 63, w = tid >> 6;
    const int lm = lane & 15, lg = lane >> 4;
    const int mrow0 = bm*32 + (w & 1)*16;
    const int nt0   = bn*4 + (w >> 1)*2;
    const int arow  = mrow0 + lm;

    f32x4 acc[2] = {{0.f,0.f,0.f,0.f},{0.f,0.f,0.f,0.f}};

#pragma unroll
    for (int kf = 0; kf < 8; ++kf) {
        const short8 ahi = *reinterpret_cast<const short8*>(
            hhi + (size_t)arow*256 + kf*32 + lg*8);
        const short8 alo = *reinterpret_cast<const short8*>(
            hlo + (size_t)arow*256 + kf*32 + lg*8);
#pragma unroll
        for (int n2 = 0; n2 < 2; ++n2) {
            const size_t foff = ((size_t)((nt0 + n2)*8 + kf)*64 + lane)*8;
            const short8 bhi = *reinterpret_cast<const short8*>(whi + foff);
            const short8 blo = *reinterpret_cast<const short8*>(wlo + foff);
            acc[n2] = __builtin_amdgcn_mfma_f32_16x16x32_bf16(ahi, bhi, acc[n2], 0, 0, 0);
            acc[n2] = __builtin_amdgcn_mfma_f32_16x16x32_bf16(alo, bhi, acc[n2], 0, 0, 0);
            acc[n2] = __builtin_amdgcn_mfma_f32_16x16x32_bf16(ahi, blo, acc[n2], 0, 0, 0);
        }
    }

#pragma unroll
    for (int n2 = 0; n2 < 2; ++n2) {
        const int col = (nt0 + n2)*16 + lm;
#pragma unroll
        for (int r = 0; r < 4; ++r) {
            const int row = mrow0 + lg*4 + r;
            float v = acc[n2][r];
            if (col < 256) {
                if (row < N_DET) Abuf[(size_t)row*256 + col] = v;
                else             Bbuf[(size_t)(row - N_DET)*256 + col] = v;
            } else {
                const int o = col - 256;
                v += pb[o];
                if (row < N_DET) {
                    const float hv = fmaxf(v + tb[o], 0.f);
                    hnext[(size_t)row*256 + o] = hv;
                    const unsigned short hb = f2bf(hv);
                    nhi[(size_t)row*256 + o] = hb;
                    nlo[(size_t)row*256 + o] = f2bf(hv - bf2f(hb));
                } else {
                    phiT[(size_t)(row - N_DET)*256 + o] = v;
                }
            }
        }
    }
}

// ---------------------------------------------------------------------------
// LDS-tiled masked column-max; also writes bf16 shadow of trk rows.
// ---------------------------------------------------------------------------
#define CM_MT 16
#define CM_OT 32
#define CM_NC 64

__global__ __launch_bounds__(256) void ec_colmax_kernel(
    const float* __restrict__ aff,
    const float* __restrict__ Abuf, const float* __restrict__ Bbuf,
    const float* __restrict__ phiT, const float* __restrict__ tb,
    float* __restrict__ hnext,
    unsigned short* __restrict__ nhi, unsigned short* __restrict__ nlo)
{
    __shared__ float As[CM_NC][CM_OT + 4];
    __shared__ float Fs[CM_NC][CM_MT + 4];
    const int t = threadIdx.x;
    const int mtile = blockIdx.x;
    const int otile = blockIdx.y;
    const int mi = t >> 4, oi = t & 15;

    float mx0 = -3.0e38f, mx1 = -3.0e38f;

    for (int n0 = 0; n0 < 512; n0 += CM_NC) {
        if (n0) __syncthreads();
        {
            const int r = t >> 3, c4 = (t & 7) * 4;
#pragma unroll
            for (int rr = 0; rr < 2; ++rr) {
                const float4 v = *(const float4*)(
                    Abuf + (size_t)(n0 + rr*32 + r)*256 + otile*CM_OT + c4);
                *(float4*)&As[rr*32 + r][c4] = v;
            }
        }
        {
            const int n = t >> 2, m4 = (t & 3) * 4;
            const float4 a = *(const float4*)(
                aff + (size_t)(n0 + n)*512 + mtile*CM_MT + m4);
            float4 f;
            f.x = (a.x > 0.f) ? 0.f : -3.0e38f;
            f.y = (a.y > 0.f) ? 0.f : -3.0e38f;
            f.z = (a.z > 0.f) ? 0.f : -3.0e38f;
            f.w = (a.w > 0.f) ? 0.f : -3.0e38f;
            *(float4*)&Fs[n][m4] = f;
        }
        __syncthreads();
#pragma unroll 4
        for (int n = 0; n < CM_NC; ++n) {
            const float f = Fs[n][mi];
            const float2 a = *(const float2*)&As[n][oi*2];
            mx0 = fmaxf(mx0, a.x + f);
            mx1 = fmaxf(mx1, a.y + f);
        }
    }

    const int m = mtile*CM_MT + mi;
    const int o = otile*CM_OT + oi*2;
    const float2 tb2 = *(const float2*)(tb + o);
    const float2 bb  = *(const float2*)(Bbuf + (size_t)m*256 + o);
    const float2 ph  = *(const float2*)(phiT + (size_t)m*256 + o);
    const float v0 = fmaxf(tb2.x, mx0 - bb.x + tb2.x);
    const float v1 = fmaxf(tb2.y, mx1 - bb.y + tb2.y);
    float2 outv;
    outv.x = fmaxf(ph.x + v0, 0.f);
    outv.y = fmaxf(ph.y + v1, 0.f);
    const size_t base = (size_t)(N_DET + m)*256 + o;
    *(float2*)(hnext + base) = outv;
    const unsigned short h0 = f2bf(outv.x), h1 = f2bf(outv.y);
    nhi[base]     = h0;
    nhi[base + 1] = h1;
    nlo[base]     = f2bf(outv.x - bf2f(h0));
    nlo[base + 1] = f2bf(outv.y - bf2f(h1));
}

// ---------------------------------------------------------------------------
// Head projection: P[1024][64] = h @ er_w1^T.
// ---------------------------------------------------------------------------
__global__ __launch_bounds__(256) void headp_kernel(
    const float* __restrict__ h, const float* __restrict__ w1, float* __restrict__ P)
{
    const int tid = threadIdx.x;
    const int o = tid & 63, rl = tid >> 6;
    const int row = blockIdx.x * 4 + rl;
    const float* hr = h + (size_t)row * 256;
    const float* wr = w1 + (size_t)o * 256;
    float s0 = 0.f, s1 = 0.f, s2 = 0.f, s3 = 0.f;
#pragma unroll
    for (int c = 0; c < 256; c += 4) {
        const float4 hv = *(const float4*)(hr + c);
        const float4 wv = *(const float4*)(wr + c);
        s0 = fmaf(hv.x, wv.x, s0);
        s1 = fmaf(hv.y, wv.y, s1);
        s2 = fmaf(hv.z, wv.z, s2);
        s3 = fmaf(hv.w, wv.w, s3);
    }
    P[(size_t)row * 64 + o] = (s0 + s1) + (s2 + s3);
}

// ---------------------------------------------------------------------------
// Pairwise affinity head.
// ---------------------------------------------------------------------------
__global__ __launch_bounds__(256) void pairwise_kernel(
    const float* __restrict__ P, const float* __restrict__ aff,
    const float* __restrict__ eb1, const float* __restrict__ ew2, const float* __restrict__ eb2,
    float* __restrict__ out)
{
    __shared__ float pd[64], sb1[64], sw2[64];
    const int n = blockIdx.y;
    const int t = threadIdx.x;
    if (t < 64)       pd[t]        = P[(size_t)n * 64 + t];
    else if (t < 128) sb1[t - 64]  = eb1[t - 64];
    else if (t < 192) sw2[t - 128] = ew2[t - 128];
    __syncthreads();
    const int m = blockIdx.x * 256 + t;
    const float* pt = P + (size_t)(N_DET + m) * 64;
    float s = eb2[0];
#pragma unroll
    for (int c = 0; c < 64; c += 4) {
        const float4 pv = *(const float4*)(pt + c);
        float e;
        e = fmaxf(pv.x - pd[c+0] + sb1[c+0], 0.f); s = fmaf(e, sw2[c+0], s);
        e = fmaxf(pv.y - pd[c+1] + sb1[c+1], 0.f); s = fmaf(e, sw2[c+1], s);
        e = fmaxf(pv.z - pd[c+2] + sb1[c+2], 0.f); s = fmaf(e, sw2[c+2], s);
        e = fmaxf(pv.w - pd[c+3] + sb1[c+3], 0.f); s = fmaf(e, sw2[c+3], s);
    }
    const float r = 1.f / (1.f + expf(-s));
    const float v = aff[(size_t)n * 512 + m] * r;
    out[(size_t)n * 512 + m] = (v == 0.f) ? 99.f : v;
}

// ---------------------------------------------------------------------------
extern "C" void kernel_launch(void* const* d_in, const int* in_sizes, int n_in,
                              void* d_out, int out_size, void* d_ws, size_t ws_size,
                              hipStream_t stream)
{
    (void)in_sizes; (void)n_in; (void)out_size; (void)ws_size;

    const float* det_pc  = (const float*)d_in[0];
    const float* det_box = (const float*)d_in[1];
    const float* trk_pc  = (const float*)d_in[2];
    const float* trk_box = (const float*)d_in[3];
    const float* aff     = (const float*)d_in[4];
    const float* pn_w1  = (const float*)d_in[6];
    const float* pn_b1  = (const float*)d_in[7];
    const float* pn_w2  = (const float*)d_in[8];
    const float* pn_b2  = (const float*)d_in[9];
    const float* pn_w3  = (const float*)d_in[10];
    const float* pn_b3  = (const float*)d_in[11];
    const float* mlp_w1 = (const float*)d_in[12];
    const float* mlp_b1 = (const float*)d_in[13];
    const float* mlp_w2 = (const float*)d_in[14];
    const float* mlp_b2 = (const float*)d_in[15];
    const float* l0_wih = (const float*)d_in[16];
    const float* l0_whh = (const float*)d_in[17];
    const float* l0_b   = (const float*)d_in[18];
    const float* l1_wih = (const float*)d_in[19];
    const float* l1_whh = (const float*)d_in[20];
    const float* l1_b   = (const float*)d_in[21];
    const float* ec_tw  = (const float*)d_in[22];
    const float* ec_tb  = (const float*)d_in[23];
    const float* ec_pw  = (const float*)d_in[24];
    const float* ec_pb  = (const float*)d_in[25];
    const float* er_w1  = (const float*)d_in[26];
    const float* er_b1  = (const float*)d_in[27];
    const float* er_w2  = (const float*)d_in[28];
    const float* er_b2  = (const float*)d_in[29];

    float* ws    = (float*)d_ws;
    float* hA    = ws;                    // [1024][256]
    float* hB    = hA + 1024*256;         // [1024][256]
    float* Abuf  = hB + 1024*256;         // [512][256]
    float* Bbuf  = Abuf + 512*256;        // [512][256]
    float* phiT  = Bbuf + 512*256;        // [512][256]
    float* P     = phiT + 512*256;        // [1024][64]
    float* xg0   = P + 1024*64;           // [5120][512]
    float* xg1   = xg0 + 5120*512;        // [5120][512]
    unsigned short* wfrag  = (unsigned short*)(xg1 + 5120*512);  // 48*64*8
    unsigned short* ecwhi  = wfrag + 48*64*8;                    // 1024*64*8
    unsigned short* ecwlo  = ecwhi + 1024*64*8;                  // 1024*64*8
    unsigned short* lstmwf = ecwlo + 1024*64*8;                  // 3*128*64*8
    unsigned short* h0hi   = lstmwf + 3*128*64*8;                // [5120][128]
    unsigned short* h0lo   = h0hi + 5120*128;
    unsigned short* hbfA_hi = h0lo + 5120*128;                   // [1024][256]
    unsigned short* hbfA_lo = hbfA_hi + 1024*256;
    unsigned short* hbfB_hi = hbfA_lo + 1024*256;
    unsigned short* hbfB_lo = hbfB_hi + 1024*256;
    // total ~32 MB

    pn_wprep_kernel<<<48, 64, 0, stream>>>(pn_w2, pn_w3, wfrag);
    ec_wprep_kernel<<<1024, 64, 0, stream>>>(ec_tw, ec_pw, ecwhi, ecwlo);
    lstm_wprep_kernel<<<384, 64, 0, stream>>>(l0_whh, l1_wih, l1_whh, lstmwf);
    pointnet_mfma_kernel<<<1024, 256, 0, stream>>>(det_pc, trk_pc, pn_w1, pn_b1,
                                                   wfrag, pn_b2, pn_b3, hA);
    detmlp_kernel<<<512, 128, 0, stream>>>(det_box, mlp_w1, mlp_b1, mlp_w2, mlp_b2, hA);

    lstm_xg0_kernel<<<640, 512, 0, stream>>>(trk_box, l0_wih, xg0);
    lstm_mfma_kernel<0><<<32, 512, 0, stream>>>(lstmwf, xg0, l0_b, h0hi, h0lo, nullptr);
    lstm_xg1_kernel<<<dim3(80, 8), 256, 0, stream>>>(h0hi, h0lo, lstmwf + 128*64*8, xg1);
    lstm_mfma_kernel<1><<<32, 512, 0, stream>>>(lstmwf + 2*128*64*8, xg1, l1_b,
                                                nullptr, nullptr, hA);

    h2bf_kernel<<<256, 256, 0, stream>>>(hA, hbfA_hi, hbfA_lo);

    float* hcur = hA;  float* hnext = hB;
    unsigned short* chi = hbfA_hi; unsigned short* clo = hbfA_lo;
    unsigned short* nhi = hbfB_hi; unsigned short* nlo = hbfB_lo;
    for (int k = 0; k < 4; ++k) {
        const float* tb = ec_tb + (size_t)k * 256;
        const float* pb = ec_pb + (size_t)k * 256;
        ec_gemm_mfma_kernel<<<dim3(32, 8), 256, 0, stream>>>(
            chi, clo, ecwhi + (size_t)k*256*64*8, ecwlo + (size_t)k*256*64*8,
            tb, pb, Abuf, Bbuf, phiT, hnext, nhi, nlo);
        ec_colmax_kernel<<<dim3(32, 8), 256, 0, stream>>>(aff, Abuf, Bbuf, phiT, tb,
                                                          hnext, nhi, nlo);
        float* tf = hcur; hcur = hnext; hnext = tf;
        unsigned short* th = chi; chi = nhi; nhi = th;
        unsigned short* tl = clo; clo = nlo; nlo = tl;
    }

    headp_kernel<<<256, 256, 0, stream>>>(hcur, er_w1, P);
    pairwise_kernel<<<dim3(2, 512), 256, 0, stream>>>(P, aff, er_b1, er_w2, er_b2,
                                                      (float*)d_out);
}

// Round 9
// 341.397 us; speedup vs baseline: 1.0231x; 1.0231x over previous
//
#include <hip/hip_runtime.h>
#include <math.h>

#define N_DET 512
#define N_TRK 512
#define NPTS  256

typedef __attribute__((ext_vector_type(8))) short short8;
typedef __attribute__((ext_vector_type(4))) float f32x4;
typedef unsigned short ushort_t;

__device__ __forceinline__ float sigm(float x) { return 1.f / (1.f + expf(-x)); }

__device__ __forceinline__ unsigned short f2bf(float f) {
    unsigned u = __float_as_uint(f);
    u += 0x7FFF + ((u >> 16) & 1);          // round-to-nearest-even
    return (unsigned short)(u >> 16);
}
__device__ __forceinline__ float bf2f(unsigned short h) {
    return __uint_as_float(((unsigned)h) << 16);
}

// ---------------------------------------------------------------------------
// Merged weight prep: blocks 0..47 pointnet w2/w3; 48..1071 EdgeConv hi/lo;
// 1072..1455 LSTM whh0/wih1/whh1.
// ---------------------------------------------------------------------------
__global__ __launch_bounds__(64) void wprep_all_kernel(
    const float* __restrict__ pnw2, const float* __restrict__ pnw3,
    const float* __restrict__ ectw, const float* __restrict__ ecpw,
    const float* __restrict__ whh0, const float* __restrict__ wih1,
    const float* __restrict__ whh1,
    unsigned short* __restrict__ wfrag,
    unsigned short* __restrict__ ecwhi, unsigned short* __restrict__ ecwlo,
    unsigned short* __restrict__ lstmwf)
{
    const int bid = blockIdx.x;
    const int lane = threadIdx.x;
    const int lm = lane & 15, lg = lane >> 4;

    if (bid < 48) {
        const int f = bid;
        const float* src;
        if (f < 16) {
            const int s = f >> 3, n = f & 7;
            src = pnw2 + (size_t)(n*16 + lm)*64 + s*32 + lg*8;
        } else {
            const int f2 = f - 16, s = f2 >> 3, n = f2 & 7;
            src = pnw3 + (size_t)(n*16 + lm)*128 + s*32 + lg*8;
        }
        short8 v;
#pragma unroll
        for (int j = 0; j < 8; ++j) v[j] = (short)f2bf(src[j]);
        *reinterpret_cast<short8*>(wfrag + ((size_t)f*64 + lane)*8) = v;
    } else if (bid < 48 + 1024) {
        const int id = bid - 48;
        const int layer = id >> 8;
        const int ntile = (id >> 3) & 31, kf = id & 7;
        const int col = ntile*16 + lm, k = kf*32 + lg*8;
        const float* src = (col < 256)
            ? ectw + ((size_t)layer*256 + col)*256 + k
            : ecpw + ((size_t)layer*256 + (col - 256))*256 + k;
        short8 hi, lo;
#pragma unroll
        for (int j = 0; j < 8; ++j) {
            const float f = src[j];
            const unsigned short h = f2bf(f);
            hi[j] = (short)h;
            lo[j] = (short)f2bf(f - bf2f(h));
        }
        const size_t off = ((size_t)id*64 + lane)*8;
        *reinterpret_cast<short8*>(ecwhi + off) = hi;
        *reinterpret_cast<short8*>(ecwlo + off) = lo;
    } else {
        const int id = bid - 1072;                  // 0..383
        const int mat = id >> 7, rest = id & 127;
        const int nt = rest >> 2, kf = rest & 3;
        const float* src = (mat == 0) ? whh0 : ((mat == 1) ? wih1 : whh1);
        const float* p = src + (size_t)(nt*16 + lm)*128 + kf*32 + lg*8;
        short8 v;
#pragma unroll
        for (int j = 0; j < 8; ++j) v[j] = (short)f2bf(p[j]);
        *reinterpret_cast<short8*>(lstmwf + ((size_t)id*64 + lane)*8) = v;
    }
}

// ---------------------------------------------------------------------------
// xg1[bt][512] = h0seq[bt][128] @ wih1^T via split-bf16 MFMA.
// ---------------------------------------------------------------------------
__global__ __launch_bounds__(256) void lstm_xg1_kernel(
    const unsigned short* __restrict__ h0hi, const unsigned short* __restrict__ h0lo,
    const unsigned short* __restrict__ wfrag, float* __restrict__ xg1)
{
    const int tid = threadIdx.x, lane = tid & 63, w = tid >> 6;
    const int lm = lane & 15, lg = lane >> 4;
    const int m0 = blockIdx.x*64 + w*16;
    const int bn = blockIdx.y;
    const int arow = m0 + lm;
    short8 ahi[4], alo[4];
#pragma unroll
    for (int kf = 0; kf < 4; ++kf) {
        ahi[kf] = *reinterpret_cast<const short8*>(h0hi + (size_t)arow*128 + kf*32 + lg*8);
        alo[kf] = *reinterpret_cast<const short8*>(h0lo + (size_t)arow*128 + kf*32 + lg*8);
    }
#pragma unroll
    for (int nt = 0; nt < 4; ++nt) {
        f32x4 acc = {0.f, 0.f, 0.f, 0.f};
#pragma unroll
        for (int kf = 0; kf < 4; ++kf) {
            const short8 bf = *reinterpret_cast<const short8*>(
                wfrag + ((size_t)((bn*4 + nt)*4 + kf)*64 + lane)*8);
            acc = __builtin_amdgcn_mfma_f32_16x16x32_bf16(ahi[kf], bf, acc, 0, 0, 0);
            acc = __builtin_amdgcn_mfma_f32_16x16x32_bf16(alo[kf], bf, acc, 0, 0, 0);
        }
#pragma unroll
        for (int r = 0; r < 4; ++r)
            xg1[(size_t)(m0 + lg*4 + r)*512 + bn*64 + nt*16 + lm] = acc[r];
    }
}

// ---------------------------------------------------------------------------
// LSTM recurrent step kernel (MFMA). 32 blocks x 512 thr, 16 batches/block.
// LAYER 0: input projection (9-wide) computed in-kernel from xseq/wih0;
//          writes h0seq hi/lo every step.
// LAYER 1: xg = precomputed h0@wih1^T; writes final h + bf16 shadow at t=9.
// ---------------------------------------------------------------------------
template<int LAYER>
__global__ __launch_bounds__(512) void lstm_mfma_kernel(
    const unsigned short* __restrict__ wfrag,
    const float* __restrict__ xg_or_xseq,   // L0: xseq [512][10][9]; L1: xg1
    const float* __restrict__ wih0,         // L0 only
    const float* __restrict__ bias,
    unsigned short* __restrict__ h0hi, unsigned short* __restrict__ h0lo,
    float* __restrict__ hout,
    unsigned short* __restrict__ nhi, unsigned short* __restrict__ nlo)
{
    __shared__ unsigned short hfhi[4*64*8];
    __shared__ unsigned short hflo[4*64*8];
    __shared__ float gs[512*20];
    __shared__ float xstage[16*10*9];          // L0 only (5.8 KB)

    const int tid = threadIdx.x;
    const int lane = tid & 63, w = tid >> 6;
    const int lm = lane & 15, lg = lane >> 4;
    const int b0 = blockIdx.x * 16;

    short8 wf[4][4];
#pragma unroll
    for (int nt = 0; nt < 4; ++nt)
#pragma unroll
        for (int kf = 0; kf < 4; ++kf)
            wf[nt][kf] = *reinterpret_cast<const short8*>(
                wfrag + ((size_t)((w*4 + nt)*4 + kf)*64 + lane)*8);

    for (int i = tid; i < 2048; i += 512) { hfhi[i] = 0; hflo[i] = 0; }

    const int mj = tid & 127;
    const int mb0 = (tid >> 7) * 4;
    const float bi = bias[mj], bf_ = bias[128 + mj];
    const float bg = bias[256 + mj], bo = bias[384 + mj];
    const int hkf = mj >> 5, hlg = (mj >> 3) & 3, hjj = mj & 7;
    float c[4] = {0.f, 0.f, 0.f, 0.f};

    float wx[4][9];
    if constexpr (LAYER == 0) {
        // stage x for 16 batches x 10 steps (1440 floats)
        for (int i = tid; i < 1440; i += 512)
            xstage[i] = xg_or_xseq[(size_t)b0*90 + i];
        // wih0 rows for this thread's 4 gate-rows
#pragma unroll
        for (int q = 0; q < 4; ++q)
#pragma unroll
            for (int cc = 0; cc < 9; ++cc)
                wx[q][cc] = wih0[(size_t)(q*128 + mj)*9 + cc];
    }

    __syncthreads();

    for (int t = 0; t < 10; ++t) {
        float xgv[4][4];
        if constexpr (LAYER == 0) {
#pragma unroll
            for (int s = 0; s < 4; ++s) {
                const float* xr = &xstage[(mb0 + s)*90 + t*9];
#pragma unroll
                for (int q = 0; q < 4; ++q) {
                    float acc = 0.f;
#pragma unroll
                    for (int cc = 0; cc < 9; ++cc) acc = fmaf(wx[q][cc], xr[cc], acc);
                    xgv[s][q] = acc;
                }
            }
        } else {
#pragma unroll
            for (int s = 0; s < 4; ++s) {
                const size_t btg = ((size_t)(b0 + mb0 + s)*10 + t)*512;
                xgv[s][0] = xg_or_xseq[btg + mj];
                xgv[s][1] = xg_or_xseq[btg + 128 + mj];
                xgv[s][2] = xg_or_xseq[btg + 256 + mj];
                xgv[s][3] = xg_or_xseq[btg + 384 + mj];
            }
        }
        short8 ahi[4], alo[4];
#pragma unroll
        for (int kf = 0; kf < 4; ++kf) {
            ahi[kf] = *reinterpret_cast<const short8*>(&hfhi[(kf*64 + lane)*8]);
            alo[kf] = *reinterpret_cast<const short8*>(&hflo[(kf*64 + lane)*8]);
        }
#pragma unroll
        for (int nt = 0; nt < 4; ++nt) {
            f32x4 acc = {0.f, 0.f, 0.f, 0.f};
#pragma unroll
            for (int kf = 0; kf < 4; ++kf) {
                acc = __builtin_amdgcn_mfma_f32_16x16x32_bf16(ahi[kf], wf[nt][kf], acc, 0, 0, 0);
                acc = __builtin_amdgcn_mfma_f32_16x16x32_bf16(alo[kf], wf[nt][kf], acc, 0, 0, 0);
            }
            const int g = w*64 + nt*16 + lm;
            float4 tmp; tmp.x = acc[0]; tmp.y = acc[1]; tmp.z = acc[2]; tmp.w = acc[3];
            *(float4*)&gs[g*20 + lg*4] = tmp;
        }
        __syncthreads();
#pragma unroll
        for (int s = 0; s < 4; ++s) {
            const int b = mb0 + s;
            const float gi = gs[mj*20 + b]         + xgv[s][0] + bi;
            const float gf = gs[(128 + mj)*20 + b] + xgv[s][1] + bf_;
            const float gg = gs[(256 + mj)*20 + b] + xgv[s][2] + bg;
            const float go = gs[(384 + mj)*20 + b] + xgv[s][3] + bo;
            c[s] = sigm(gf)*c[s] + sigm(gi)*tanhf(gg);
            const float hn = sigm(go)*tanhf(c[s]);
            const unsigned short hh = f2bf(hn);
            const unsigned short hl = f2bf(hn - bf2f(hh));
            hfhi[(hkf*64 + hlg*16 + b)*8 + hjj] = hh;
            hflo[(hkf*64 + hlg*16 + b)*8 + hjj] = hl;
            if constexpr (LAYER == 0) {
                h0hi[((size_t)(b0 + b)*10 + t)*128 + mj] = hh;
                h0lo[((size_t)(b0 + b)*10 + t)*128 + mj] = hl;
            } else {
                if (t == 9) {
                    const size_t base = (size_t)(N_DET + b0 + b)*256 + 128 + mj;
                    hout[base] = hn;
                    nhi[base] = hh;
                    nlo[base] = hl;
                }
            }
        }
        __syncthreads();
    }
}

// ---------------------------------------------------------------------------
// PointNet fused MFMA kernel, tile-streamed LDS (one box/block, 4 waves).
// Writes fp32 h + split-bf16 shadow directly.
// ---------------------------------------------------------------------------
__global__ __launch_bounds__(256) void pointnet_mfma_kernel(
    const float* __restrict__ det_pc, const float* __restrict__ trk_pc,
    const float* __restrict__ w1, const float* __restrict__ b1,
    const unsigned short* __restrict__ wfrag,
    const float* __restrict__ b2, const float* __restrict__ b3,
    float* __restrict__ hout,
    unsigned short* __restrict__ nhi, unsigned short* __restrict__ nlo)
{
    __shared__ unsigned short h1t[4][16][72];
    __shared__ unsigned short h2t[4][16][136];
    __shared__ float wmaxs[4][128];

    const int tid = threadIdx.x;
    const int box = blockIdx.x;
    const int lane = tid & 63, w = tid >> 6;
    const int lm = lane & 15, lg = lane >> 4;

    const float* pc = (box < N_DET) ? det_pc + ((size_t)box*NPTS + tid)*3
                                    : trk_pc + ((size_t)(box - N_DET)*NPTS + tid)*3;
    const float x = pc[0], y = pc[1], z = pc[2];
    unsigned h1p[32];
#pragma unroll
    for (int j = 0; j < 32; ++j) {
        const int c0 = 2*j, c1 = 2*j + 1;
        float s0 = fmaf(w1[c0*3+0], x, fmaf(w1[c0*3+1], y, fmaf(w1[c0*3+2], z, b1[c0])));
        float s1 = fmaf(w1[c1*3+0], x, fmaf(w1[c1*3+1], y, fmaf(w1[c1*3+2], z, b1[c1])));
        h1p[j] = (unsigned)f2bf(fmaxf(s0, 0.f)) | ((unsigned)f2bf(fmaxf(s1, 0.f)) << 16);
    }

    short8 w2f[16];
#pragma unroll
    for (int f = 0; f < 16; ++f)
        w2f[f] = *reinterpret_cast<const short8*>(wfrag + ((size_t)f*64 + lane)*8);
    float b2v[8];
#pragma unroll
    for (int n = 0; n < 8; ++n) b2v[n] = b2[n*16 + lm];

    float pm[8];
#pragma unroll
    for (int n = 0; n < 8; ++n) pm[n] = -3.0e38f;

    for (int t = 0; t < 4; ++t) {
        __syncthreads();
        if (lg == t) {
#pragma unroll
            for (int q = 0; q < 8; ++q) {
                uint4 v;
                v.x = h1p[q*4+0]; v.y = h1p[q*4+1];
                v.z = h1p[q*4+2]; v.w = h1p[q*4+3];
                *(uint4*)&h1t[w][lm][q*8] = v;
            }
        }
        __syncthreads();
        const short8 a0 = *reinterpret_cast<const short8*>(&h1t[w][lm][lg*8]);
        const short8 a1 = *reinterpret_cast<const short8*>(&h1t[w][lm][32 + lg*8]);
#pragma unroll
        for (int n = 0; n < 8; ++n) {
            f32x4 acc = {0.f, 0.f, 0.f, 0.f};
            acc = __builtin_amdgcn_mfma_f32_16x16x32_bf16(a0, w2f[n],     acc, 0, 0, 0);
            acc = __builtin_amdgcn_mfma_f32_16x16x32_bf16(a1, w2f[8 + n], acc, 0, 0, 0);
#pragma unroll
            for (int r = 0; r < 4; ++r) {
                const float v = fmaxf(acc[r] + b2v[n], 0.f);
                h2t[w][lg*4 + r][n*16 + lm] = f2bf(v);
            }
        }
        __syncthreads();
        const short8 c0 = *reinterpret_cast<const short8*>(&h2t[w][lm][  0 + lg*8]);
        const short8 c1 = *reinterpret_cast<const short8*>(&h2t[w][lm][ 32 + lg*8]);
        const short8 c2 = *reinterpret_cast<const short8*>(&h2t[w][lm][ 64 + lg*8]);
        const short8 c3 = *reinterpret_cast<const short8*>(&h2t[w][lm][ 96 + lg*8]);
#pragma unroll
        for (int n = 0; n < 8; ++n) {
            f32x4 acc = {0.f, 0.f, 0.f, 0.f};
            const short8 b0f = *reinterpret_cast<const short8*>(wfrag + ((size_t)(16 +      n)*64 + lane)*8);
            const short8 b1f = *reinterpret_cast<const short8*>(wfrag + ((size_t)(16 +  8 + n)*64 + lane)*8);
            const short8 b2f = *reinterpret_cast<const short8*>(wfrag + ((size_t)(16 + 16 + n)*64 + lane)*8);
            const short8 b3f = *reinterpret_cast<const short8*>(wfrag + ((size_t)(16 + 24 + n)*64 + lane)*8);
            acc = __builtin_amdgcn_mfma_f32_16x16x32_bf16(c0, b0f, acc, 0, 0, 0);
            acc = __builtin_amdgcn_mfma_f32_16x16x32_bf16(c1, b1f, acc, 0, 0, 0);
            acc = __builtin_amdgcn_mfma_f32_16x16x32_bf16(c2, b2f, acc, 0, 0, 0);
            acc = __builtin_amdgcn_mfma_f32_16x16x32_bf16(c3, b3f, acc, 0, 0, 0);
#pragma unroll
            for (int r = 0; r < 4; ++r) pm[n] = fmaxf(pm[n], acc[r]);
        }
    }

#pragma unroll
    for (int n = 0; n < 8; ++n) {
        float v = pm[n];
        v = fmaxf(v, __shfl_xor(v, 16, 64));
        v = fmaxf(v, __shfl_xor(v, 32, 64));
        pm[n] = v;
    }
    if (lg == 0) {
#pragma unroll
        for (int n = 0; n < 8; ++n) wmaxs[w][n*16 + lm] = pm[n];
    }
    __syncthreads();
    if (tid < 128) {
        const float m = fmaxf(fmaxf(wmaxs[0][tid], wmaxs[1][tid]),
                              fmaxf(wmaxs[2][tid], wmaxs[3][tid]));
        const float v = fmaxf(m + b3[tid], 0.f);
        const size_t base = (size_t)box*256 + tid;
        hout[base] = v;
        const unsigned short hh = f2bf(v);
        nhi[base] = hh;
        nlo[base] = f2bf(v - bf2f(hh));
    }
}

// ---------------------------------------------------------------------------
// det motion MLP: 9 -> 64 (relu) -> 128; writes fp32 + bf16 shadow.
// ---------------------------------------------------------------------------
__global__ __launch_bounds__(128) void detmlp_kernel(
    const float* __restrict__ boxes,
    const float* __restrict__ w1, const float* __restrict__ b1,
    const float* __restrict__ w2, const float* __restrict__ b2,
    float* __restrict__ hout,
    unsigned short* __restrict__ nhi, unsigned short* __restrict__ nlo)
{
    __shared__ float xb[9];
    __shared__ float h1[64];
    const int b = blockIdx.x, t = threadIdx.x;
    if (t < 9) xb[t] = boxes[b*9 + t];
    __syncthreads();
    if (t < 64) {
        float s = b1[t];
#pragma unroll
        for (int c = 0; c < 9; ++c) s = fmaf(w1[t*9+c], xb[c], s);
        h1[t] = fmaxf(s, 0.f);
    }
    __syncthreads();
    float s = b2[t];
    const float* wr = w2 + t*64;
#pragma unroll
    for (int c = 0; c < 64; ++c) s = fmaf(wr[c], h1[c], s);
    const size_t base = (size_t)b * 256 + 128 + t;
    hout[base] = s;
    const unsigned short hh = f2bf(s);
    nhi[base] = hh;
    nlo[base] = f2bf(s - bf2f(hh));
}

// ---------------------------------------------------------------------------
// EdgeConv GEMM via split-bf16 MFMA (3-product, fp32-grade).
// ---------------------------------------------------------------------------
__global__ __launch_bounds__(256) void ec_gemm_mfma_kernel(
    const unsigned short* __restrict__ hhi, const unsigned short* __restrict__ hlo,
    const unsigned short* __restrict__ whi, const unsigned short* __restrict__ wlo,
    const float* __restrict__ tb, const float* __restrict__ pb,
    float* __restrict__ Abuf, float* __restrict__ Bbuf,
    float* __restrict__ phiT, float* __restrict__ hnext,
    unsigned short* __restrict__ nhi, unsigned short* __restrict__ nlo)
{
    const int bm = blockIdx.x, bn = blockIdx.y;
    const int tid = threadIdx.x, lane = tid & 63, w = tid >> 6;
    const int lm = lane & 15, lg = lane >> 4;
    const int mrow0 = bm*32 + (w & 1)*16;
    const int nt0   = bn*4 + (w >> 1)*2;
    const int arow  = mrow0 + lm;

    f32x4 acc[2] = {{0.f,0.f,0.f,0.f},{0.f,0.f,0.f,0.f}};

#pragma unroll
    for (int kf = 0; kf < 8; ++kf) {
        const short8 ahi = *reinterpret_cast<const short8*>(
            hhi + (size_t)arow*256 + kf*32 + lg*8);
        const short8 alo = *reinterpret_cast<const short8*>(
            hlo + (size_t)arow*256 + kf*32 + lg*8);
#pragma unroll
        for (int n2 = 0; n2 < 2; ++n2) {
            const size_t foff = ((size_t)((nt0 + n2)*8 + kf)*64 + lane)*8;
            const short8 bhi = *reinterpret_cast<const short8*>(whi + foff);
            const short8 blo = *reinterpret_cast<const short8*>(wlo + foff);
            acc[n2] = __builtin_amdgcn_mfma_f32_16x16x32_bf16(ahi, bhi, acc[n2], 0, 0, 0);
            acc[n2] = __builtin_amdgcn_mfma_f32_16x16x32_bf16(alo, bhi, acc[n2], 0, 0, 0);
            acc[n2] = __builtin_amdgcn_mfma_f32_16x16x32_bf16(ahi, blo, acc[n2], 0, 0, 0);
        }
    }

#pragma unroll
    for (int n2 = 0; n2 < 2; ++n2) {
        const int col = (nt0 + n2)*16 + lm;
#pragma unroll
        for (int r = 0; r < 4; ++r) {
            const int row = mrow0 + lg*4 + r;
            float v = acc[n2][r];
            if (col < 256) {
                if (row < N_DET) Abuf[(size_t)row*256 + col] = v;
                else             Bbuf[(size_t)(row - N_DET)*256 + col] = v;
            } else {
                const int o = col - 256;
                v += pb[o];
                if (row < N_DET) {
                    const float hv = fmaxf(v + tb[o], 0.f);
                    hnext[(size_t)row*256 + o] = hv;
                    const unsigned short hb = f2bf(hv);
                    nhi[(size_t)row*256 + o] = hb;
                    nlo[(size_t)row*256 + o] = f2bf(hv - bf2f(hb));
                } else {
                    phiT[(size_t)(row - N_DET)*256 + o] = v;
                }
            }
        }
    }
}

// ---------------------------------------------------------------------------
// LDS-tiled masked column-max; also writes bf16 shadow of trk rows.
// ---------------------------------------------------------------------------
#define CM_MT 16
#define CM_OT 32
#define CM_NC 64

__global__ __launch_bounds__(256) void ec_colmax_kernel(
    const float* __restrict__ aff,
    const float* __restrict__ Abuf, const float* __restrict__ Bbuf,
    const float* __restrict__ phiT, const float* __restrict__ tb,
    float* __restrict__ hnext,
    unsigned short* __restrict__ nhi, unsigned short* __restrict__ nlo)
{
    __shared__ float As[CM_NC][CM_OT + 4];
    __shared__ float Fs[CM_NC][CM_MT + 4];
    const int t = threadIdx.x;
    const int mtile = blockIdx.x;
    const int otile = blockIdx.y;
    const int mi = t >> 4, oi = t & 15;

    float mx0 = -3.0e38f, mx1 = -3.0e38f;

    for (int n0 = 0; n0 < 512; n0 += CM_NC) {
        if (n0) __syncthreads();
        {
            const int r = t >> 3, c4 = (t & 7) * 4;
#pragma unroll
            for (int rr = 0; rr < 2; ++rr) {
                const float4 v = *(const float4*)(
                    Abuf + (size_t)(n0 + rr*32 + r)*256 + otile*CM_OT + c4);
                *(float4*)&As[rr*32 + r][c4] = v;
            }
        }
        {
            const int n = t >> 2, m4 = (t & 3) * 4;
            const float4 a = *(const float4*)(
                aff + (size_t)(n0 + n)*512 + mtile*CM_MT + m4);
            float4 f;
            f.x = (a.x > 0.f) ? 0.f : -3.0e38f;
            f.y = (a.y > 0.f) ? 0.f : -3.0e38f;
            f.z = (a.z > 0.f) ? 0.f : -3.0e38f;
            f.w = (a.w > 0.f) ? 0.f : -3.0e38f;
            *(float4*)&Fs[n][m4] = f;
        }
        __syncthreads();
#pragma unroll 4
        for (int n = 0; n < CM_NC; ++n) {
            const float f = Fs[n][mi];
            const float2 a = *(const float2*)&As[n][oi*2];
            mx0 = fmaxf(mx0, a.x + f);
            mx1 = fmaxf(mx1, a.y + f);
        }
    }

    const int m = mtile*CM_MT + mi;
    const int o = otile*CM_OT + oi*2;
    const float2 tb2 = *(const float2*)(tb + o);
    const float2 bb  = *(const float2*)(Bbuf + (size_t)m*256 + o);
    const float2 ph  = *(const float2*)(phiT + (size_t)m*256 + o);
    const float v0 = fmaxf(tb2.x, mx0 - bb.x + tb2.x);
    const float v1 = fmaxf(tb2.y, mx1 - bb.y + tb2.y);
    float2 outv;
    outv.x = fmaxf(ph.x + v0, 0.f);
    outv.y = fmaxf(ph.y + v1, 0.f);
    const size_t base = (size_t)(N_DET + m)*256 + o;
    *(float2*)(hnext + base) = outv;
    const unsigned short h0 = f2bf(outv.x), h1 = f2bf(outv.y);
    nhi[base]     = h0;
    nhi[base + 1] = h1;
    nlo[base]     = f2bf(outv.x - bf2f(h0));
    nlo[base + 1] = f2bf(outv.y - bf2f(h1));
}

// ---------------------------------------------------------------------------
// Head projection: P[1024][64] = h @ er_w1^T.
// ---------------------------------------------------------------------------
__global__ __launch_bounds__(256) void headp_kernel(
    const float* __restrict__ h, const float* __restrict__ w1, float* __restrict__ P)
{
    const int tid = threadIdx.x;
    const int o = tid & 63, rl = tid >> 6;
    const int row = blockIdx.x * 4 + rl;
    const float* hr = h + (size_t)row * 256;
    const float* wr = w1 + (size_t)o * 256;
    float s0 = 0.f, s1 = 0.f, s2 = 0.f, s3 = 0.f;
#pragma unroll
    for (int c = 0; c < 256; c += 4) {
        const float4 hv = *(const float4*)(hr + c);
        const float4 wv = *(const float4*)(wr + c);
        s0 = fmaf(hv.x, wv.x, s0);
        s1 = fmaf(hv.y, wv.y, s1);
        s2 = fmaf(hv.z, wv.z, s2);
        s3 = fmaf(hv.w, wv.w, s3);
    }
    P[(size_t)row * 64 + o] = (s0 + s1) + (s2 + s3);
}

// ---------------------------------------------------------------------------
// Pairwise affinity head.
// ---------------------------------------------------------------------------
__global__ __launch_bounds__(256) void pairwise_kernel(
    const float* __restrict__ P, const float* __restrict__ aff,
    const float* __restrict__ eb1, const float* __restrict__ ew2, const float* __restrict__ eb2,
    float* __restrict__ out)
{
    __shared__ float pd[64], sb1[64], sw2[64];
    const int n = blockIdx.y;
    const int t = threadIdx.x;
    if (t < 64)       pd[t]        = P[(size_t)n * 64 + t];
    else if (t < 128) sb1[t - 64]  = eb1[t - 64];
    else if (t < 192) sw2[t - 128] = ew2[t - 128];
    __syncthreads();
    const int m = blockIdx.x * 256 + t;
    const float* pt = P + (size_t)(N_DET + m) * 64;
    float s = eb2[0];
#pragma unroll
    for (int c = 0; c < 64; c += 4) {
        const float4 pv = *(const float4*)(pt + c);
        float e;
        e = fmaxf(pv.x - pd[c+0] + sb1[c+0], 0.f); s = fmaf(e, sw2[c+0], s);
        e = fmaxf(pv.y - pd[c+1] + sb1[c+1], 0.f); s = fmaf(e, sw2[c+1], s);
        e = fmaxf(pv.z - pd[c+2] + sb1[c+2], 0.f); s = fmaf(e, sw2[c+2], s);
        e = fmaxf(pv.w - pd[c+3] + sb1[c+3], 0.f); s = fmaf(e, sw2[c+3], s);
    }
    const float r = 1.f / (1.f + expf(-s));
    const float v = aff[(size_t)n * 512 + m] * r;
    out[(size_t)n * 512 + m] = (v == 0.f) ? 99.f : v;
}

// ---------------------------------------------------------------------------
extern "C" void kernel_launch(void* const* d_in, const int* in_sizes, int n_in,
                              void* d_out, int out_size, void* d_ws, size_t ws_size,
                              hipStream_t stream)
{
    (void)in_sizes; (void)n_in; (void)out_size; (void)ws_size;

    const float* det_pc  = (const float*)d_in[0];
    const float* det_box = (const float*)d_in[1];
    const float* trk_pc  = (const float*)d_in[2];
    const float* trk_box = (const float*)d_in[3];
    const float* aff     = (const float*)d_in[4];
    const float* pn_w1  = (const float*)d_in[6];
    const float* pn_b1  = (const float*)d_in[7];
    const float* pn_w2  = (const float*)d_in[8];
    const float* pn_b2  = (const float*)d_in[9];
    const float* pn_w3  = (const float*)d_in[10];
    const float* pn_b3  = (const float*)d_in[11];
    const float* mlp_w1 = (const float*)d_in[12];
    const float* mlp_b1 = (const float*)d_in[13];
    const float* mlp_w2 = (const float*)d_in[14];
    const float* mlp_b2 = (const float*)d_in[15];
    const float* l0_wih = (const float*)d_in[16];
    const float* l0_whh = (const float*)d_in[17];
    const float* l0_b   = (const float*)d_in[18];
    const float* l1_wih = (const float*)d_in[19];
    const float* l1_whh = (const float*)d_in[20];
    const float* l1_b   = (const float*)d_in[21];
    const float* ec_tw  = (const float*)d_in[22];
    const float* ec_tb  = (const float*)d_in[23];
    const float* ec_pw  = (const float*)d_in[24];
    const float* ec_pb  = (const float*)d_in[25];
    const float* er_w1  = (const float*)d_in[26];
    const float* er_b1  = (const float*)d_in[27];
    const float* er_w2  = (const float*)d_in[28];
    const float* er_b2  = (const float*)d_in[29];

    float* ws    = (float*)d_ws;
    float* hA    = ws;                    // [1024][256]
    float* hB    = hA + 1024*256;         // [1024][256]
    float* Abuf  = hB + 1024*256;         // [512][256]
    float* Bbuf  = Abuf + 512*256;        // [512][256]
    float* phiT  = Bbuf + 512*256;        // [512][256]
    float* P     = phiT + 512*256;        // [1024][64]
    float* xg1   = P + 1024*64;           // [5120][512]
    unsigned short* wfrag  = (unsigned short*)(xg1 + 5120*512);  // 48*64*8
    unsigned short* ecwhi  = wfrag + 48*64*8;                    // 1024*64*8
    unsigned short* ecwlo  = ecwhi + 1024*64*8;                  // 1024*64*8
    unsigned short* lstmwf = ecwlo + 1024*64*8;                  // 3*128*64*8
    unsigned short* h0hi   = lstmwf + 3*128*64*8;                // [5120][128]
    unsigned short* h0lo   = h0hi + 5120*128;
    unsigned short* hbfA_hi = h0lo + 5120*128;                   // [1024][256]
    unsigned short* hbfA_lo = hbfA_hi + 1024*256;
    unsigned short* hbfB_hi = hbfA_lo + 1024*256;
    unsigned short* hbfB_lo = hbfB_hi + 1024*256;
    // total ~22 MB

    wprep_all_kernel<<<1456, 64, 0, stream>>>(pn_w2, pn_w3, ec_tw, ec_pw,
                                              l0_whh, l1_wih, l1_whh,
                                              wfrag, ecwhi, ecwlo, lstmwf);
    pointnet_mfma_kernel<<<1024, 256, 0, stream>>>(det_pc, trk_pc, pn_w1, pn_b1,
                                                   wfrag, pn_b2, pn_b3, hA,
                                                   hbfA_hi, hbfA_lo);
    detmlp_kernel<<<512, 128, 0, stream>>>(det_box, mlp_w1, mlp_b1, mlp_w2, mlp_b2,
                                           hA, hbfA_hi, hbfA_lo);

    lstm_mfma_kernel<0><<<32, 512, 0, stream>>>(lstmwf, trk_box, l0_wih, l0_b,
                                                h0hi, h0lo, nullptr, nullptr, nullptr);
    lstm_xg1_kernel<<<dim3(80, 8), 256, 0, stream>>>(h0hi, h0lo, lstmwf + 128*64*8, xg1);
    lstm_mfma_kernel<1><<<32, 512, 0, stream>>>(lstmwf + 2*128*64*8, xg1, nullptr, l1_b,
                                                nullptr, nullptr, hA, hbfA_hi, hbfA_lo);

    float* hcur = hA;  float* hnext = hB;
    unsigned short* chi = hbfA_hi; unsigned short* clo = hbfA_lo;
    unsigned short* nhi = hbfB_hi; unsigned short* nlo = hbfB_lo;
    for (int k = 0; k < 4; ++k) {
        const float* tb = ec_tb + (size_t)k * 256;
        const float* pb = ec_pb + (size_t)k * 256;
        ec_gemm_mfma_kernel<<<dim3(32, 8), 256, 0, stream>>>(
            chi, clo, ecwhi + (size_t)k*256*64*8, ecwlo + (size_t)k*256*64*8,
            tb, pb, Abuf, Bbuf, phiT, hnext, nhi, nlo);
        ec_colmax_kernel<<<dim3(32, 8), 256, 0, stream>>>(aff, Abuf, Bbuf, phiT, tb,
                                                          hnext, nhi, nlo);
        float* tf = hcur; hcur = hnext; hnext = tf;
        unsigned short* th = chi; chi = nhi; nhi = th;
        unsigned short* tl = clo; clo = nlo; nlo = tl;
    }

    headp_kernel<<<256, 256, 0, stream>>>(hcur, er_w1, P);
    pairwise_kernel<<<dim3(2, 512), 256, 0, stream>>>(P, aff, er_b1, er_w2, er_b2,
                                                      (float*)d_out);
}